// Round 13
// baseline (267.594 us; speedup 1.0000x reference)
//
#include <hip/hip_runtime.h>
#include <cstdint>
#include <cstddef>

// ---------------------------------------------------------------------------
// MultiheadAttention (double-softmax), MI355X. B=4,S=1024,D=1024,H=16.
// Inputs FP32 (dict order), output FP32. r9:317 r10:328 r12:264.7 µs.
// r13: (1) all weights pre-cvt to bf16 (qkv B-staging = pure copy, no VALU
// cvt); (2) qkv 64x128 tiles, grid 1536 = 6 blocks/CU (24 waves/CU, was 12);
// (3) pre-LN buffer bf16 (halves outp-write + ln-read traffic).
//   K0 cvt4: Wo,Wq,Wk,Wv fp32->bf16 into d_out[0,8MB) (dead until ln)
//   K1 qkv : q,k -> [B,S,D] bf16 (q*0.125); v -> [B,H,dk,S] bf16
//   K2 attn: two-pass double softmax, no-max softmax1 (scores << 88)
//   K3 outp: 64x128 tiles, ctx @ Wo_bf^T + bo -> pre bf16
//   K4 ln  : LayerNorm(pre + Q)*g + b -> d_out f32 [0,16MB)
// ws (24 MB): qb[0,8) kb[8,16) vb[16,24); pre bf16 aliases [0,8) (qb dead).
// d_out u16 view: wo[0,1M) wq[1M,2M) wk[2M,3M) wv[3M,4M) ctx[4M,8M).
// ---------------------------------------------------------------------------

typedef unsigned short ushort_t;
typedef __attribute__((ext_vector_type(8))) short bf16x8;     // MFMA A/B frag
typedef __attribute__((ext_vector_type(8))) unsigned short us8;
typedef __attribute__((ext_vector_type(4))) unsigned short us4;
typedef __attribute__((ext_vector_type(4))) float f32x4;      // MFMA C/D frag

#define MFMA16(a, b, c) __builtin_amdgcn_mfma_f32_16x16x32_bf16((a), (b), (c), 0, 0, 0)

__device__ __forceinline__ float b2f(ushort_t u) {
  union { unsigned int i; float f; } x; x.i = ((unsigned int)u) << 16; return x.f;
}
__device__ __forceinline__ ushort_t f2b(float f) {
  union { unsigned int i; float f; } x; x.f = f;
  unsigned int r = (x.i + 0x7FFFu + ((x.i >> 16) & 1u)) >> 16;  // RNE
  return (ushort_t)r;
}
__device__ __forceinline__ us8 cvt8(float4 a, float4 b) {
  us8 r;
  r[0] = f2b(a.x); r[1] = f2b(a.y); r[2] = f2b(a.z); r[3] = f2b(a.w);
  r[4] = f2b(b.x); r[5] = f2b(b.y); r[6] = f2b(b.z); r[7] = f2b(b.w);
  return r;
}

// ---------------------------------------------------------------------------
// K0: convert 4 weight matrices (1M fp32 elems each) to bf16.
// dst elem layout: [0,1M)=w0, [1M,2M)=w1, [2M,3M)=w2, [3M,4M)=w3.
// ---------------------------------------------------------------------------
__global__ __launch_bounds__(256, 8) void cvt4_kernel(
    const float* __restrict__ w0, const float* __restrict__ w1,
    const float* __restrict__ w2, const float* __restrict__ w3,
    ushort_t* __restrict__ dst) {
  const int which = blockIdx.y;
  const float* src = (which == 0) ? w0 : (which == 1) ? w1 : (which == 2) ? w2 : w3;
  const int i = (blockIdx.x * 256 + threadIdx.x) * 8;
  const float4 a = *(const float4*)(src + i);
  const float4 b = *(const float4*)(src + i + 4);
  *(us8*)(dst + (size_t)which * 1048576 + i) = cvt8(a, b);
}

// ---------------------------------------------------------------------------
// K1: Q/K/V projections. 64x128 tiles, grid (8,64,3) = 1536 blocks (6/CU).
// A = fp32 input (cvt in staging, prefetched); B = bf16 weight (pure copy).
// Wave w: rows 0..63 (ms 0..3), cols w*32 (ns 0..1).
// q,k -> [B,S,D]; v -> [B,H,dk,S] (transposed per head).
// ---------------------------------------------------------------------------
__global__ __launch_bounds__(256, 6) void qkv_proj_kernel(
    const float* __restrict__ Qin, const float* __restrict__ Kin,
    const float* __restrict__ Vin,
    const ushort_t* __restrict__ wq, const ushort_t* __restrict__ wk,
    const ushort_t* __restrict__ wv,
    const float* __restrict__ bq, const float* __restrict__ bk,
    const float* __restrict__ bv,
    ushort_t* __restrict__ qb, ushort_t* __restrict__ kb,
    ushort_t* __restrict__ vb) {
  __shared__ __align__(16) ushort_t Asl[64 * 32];
  __shared__ __align__(16) ushort_t Bsl[128 * 32];
  const float* A; const ushort_t* W; const float* bias; float scale;
  if (blockIdx.z == 0)      { A = Qin; W = wq; bias = bq; scale = 0.125f; }
  else if (blockIdx.z == 1) { A = Kin; W = wk; bias = bk; scale = 1.0f; }
  else                      { A = Vin; W = wv; bias = bv; scale = 1.0f; }
  const int m0 = blockIdx.y * 64, n0 = blockIdx.x * 128;
  const int tid = threadIdx.x;
  const int wave = tid >> 6, lane = tid & 63;
  const int l15 = lane & 15, quad = lane >> 4;
  const int wn = wave * 32;

  // chunk geometry: chunk c: row = c>>2, col = (c&3)*8
  const int ra = tid >> 2, ca = (tid & 3) * 8;
  const int rb1 = (tid + 256) >> 2;                    // B rows 64..127

  const float* Ap = A + (size_t)(m0 + ra) * 1024 + ca;
  const ushort_t* Bp0 = W + (size_t)(n0 + ra) * 1024 + ca;
  const ushort_t* Bp1 = W + (size_t)(n0 + rb1) * 1024 + ca;

  float4 al = *(const float4*)(Ap), ah = *(const float4*)(Ap + 4);
  us8 rb0v = *(const us8*)(Bp0);
  us8 rb1v = *(const us8*)(Bp1);

  f32x4 acc[4][2] = {};
  for (int k0 = 0; k0 < 1024; k0 += 32) {
    __syncthreads();
    *(us8*)(Asl + ra * 32 + ca) = cvt8(al, ah);
    *(us8*)(Bsl + ra * 32 + ca) = rb0v;
    *(us8*)(Bsl + rb1 * 32 + ca) = rb1v;
    __syncthreads();
    if (k0 + 32 < 1024) {  // prefetch next K-tile (overlaps MFMA)
      const int k = k0 + 32;
      al = *(const float4*)(Ap + k); ah = *(const float4*)(Ap + k + 4);
      rb0v = *(const us8*)(Bp0 + k);
      rb1v = *(const us8*)(Bp1 + k);
    }
    bf16x8 af[4], bfr[2];
#pragma unroll
    for (int s = 0; s < 4; ++s)
      af[s] = *(const bf16x8*)(Asl + (s * 16 + l15) * 32 + quad * 8);
#pragma unroll
    for (int s = 0; s < 2; ++s)
      bfr[s] = *(const bf16x8*)(Bsl + (wn + s * 16 + l15) * 32 + quad * 8);
#pragma unroll
    for (int ms = 0; ms < 4; ++ms)
#pragma unroll
      for (int ns = 0; ns < 2; ++ns)
        acc[ms][ns] = MFMA16(af[ms], bfr[ns], acc[ms][ns]);
  }

  if (blockIdx.z != 2) {
    ushort_t* outp = (blockIdx.z == 0) ? qb : kb;
#pragma unroll
    for (int ns = 0; ns < 2; ++ns) {
      const int col = n0 + wn + ns * 16 + l15;
      const float bv_ = bias[col];
#pragma unroll
      for (int ms = 0; ms < 4; ++ms) {
        const int rowb = m0 + ms * 16 + quad * 4;
#pragma unroll
        for (int r = 0; r < 4; ++r) {
          outp[(size_t)(rowb + r) * 1024 + col] =
              f2b((acc[ms][ns][r] + bv_) * scale);
        }
      }
    }
  } else {
    // V transposed: vb[((b*16+h)*64 + d)*1024 + s]
#pragma unroll
    for (int ns = 0; ns < 2; ++ns) {
      const int col = n0 + wn + ns * 16 + l15;
      const float bv_ = bias[col];
      const int h = col >> 6, d = col & 63;
#pragma unroll
      for (int ms = 0; ms < 4; ++ms) {
        const int i0 = m0 + ms * 16 + quad * 4;
        const int b = i0 >> 10, s0 = i0 & 1023;
        us4 pack;
#pragma unroll
        for (int r = 0; r < 4; ++r) pack[r] = f2b(acc[ms][ns][r] + bv_);
        *(us4*)(vb + ((size_t)(b * 16 + h) * 64 + d) * 1024 + s0) = pack;
      }
    }
  }
}

// ---------------------------------------------------------------------------
// K2: attention, double softmax. 64-row Q tile, grid (16,64) = 1024 blocks.
// Pass 1: Z1 = sum(exp(s)) only (no max). Pass 2: e2 = exp(exp(s)/Z1), PV.
// K/V staging register-prefetch pipelined. V pre-transposed [B,H,dk,S].
// ---------------------------------------------------------------------------
__global__ __launch_bounds__(256, 4) void attn_kernel(
    const ushort_t* __restrict__ qb, const ushort_t* __restrict__ kb,
    const ushort_t* __restrict__ vb, ushort_t* __restrict__ ctx) {
  __shared__ __align__(16) ushort_t Qs[64 * 72];
  __shared__ __align__(16) ushort_t Ks[64 * 72];
  __shared__ __align__(16) ushort_t Vt[64 * 72];
  __shared__ __align__(16) ushort_t Ps[4][16 * 68];

  const int tid = threadIdx.x, wave = tid >> 6, lane = tid & 63;
  const int l15 = lane & 15, quad = lane >> 4;
  const int bh = blockIdx.y;
  const int b = bh >> 4, h = bh & 15;
  const int q0 = blockIdx.x * 64;
  const ushort_t* qg = qb + ((size_t)b << 20) + h * 64;
  const ushort_t* kg = kb + ((size_t)b << 20) + h * 64;
  const ushort_t* vg = vb + ((size_t)bh << 16);   // [dk][S]

  const int kr0 = tid >> 3, kc0 = (tid & 7) * 8;
  const int kr1 = (tid + 256) >> 3, kc1 = kc0;

  *(us8*)(Qs + kr0 * 72 + kc0) = *(const us8*)(qg + (size_t)(q0 + kr0) * 1024 + kc0);
  *(us8*)(Qs + kr1 * 72 + kc1) = *(const us8*)(qg + (size_t)(q0 + kr1) * 1024 + kc1);

  // ---- pass 1: Z1 only ----
  float z1[4] = {0.f, 0.f, 0.f, 0.f};
  us8 rk0 = *(const us8*)(kg + (size_t)kr0 * 1024 + kc0);
  us8 rk1 = *(const us8*)(kg + (size_t)kr1 * 1024 + kc1);
  for (int kt = 0; kt < 16; ++kt) {
    __syncthreads();
    *(us8*)(Ks + kr0 * 72 + kc0) = rk0;
    *(us8*)(Ks + kr1 * 72 + kc1) = rk1;
    __syncthreads();
    if (kt < 15) {
      rk0 = *(const us8*)(kg + (size_t)((kt + 1) * 64 + kr0) * 1024 + kc0);
      rk1 = *(const us8*)(kg + (size_t)((kt + 1) * 64 + kr1) * 1024 + kc1);
    }
    f32x4 sc[4] = {};
#pragma unroll
    for (int kk = 0; kk < 2; ++kk) {
      const bf16x8 aq = *(const bf16x8*)(Qs + (wave * 16 + l15) * 72 + kk * 32 + quad * 8);
#pragma unroll
      for (int ns = 0; ns < 4; ++ns) {
        const bf16x8 bk_ = *(const bf16x8*)(Ks + (ns * 16 + l15) * 72 + kk * 32 + quad * 8);
        sc[ns] = MFMA16(aq, bk_, sc[ns]);
      }
    }
#pragma unroll
    for (int ns = 0; ns < 4; ++ns)
#pragma unroll
      for (int r = 0; r < 4; ++r) z1[r] += __expf(sc[ns][r]);
  }
  float iz1[4];
#pragma unroll
  for (int r = 0; r < 4; ++r) {
    float s = z1[r];
#pragma unroll
    for (int off = 1; off < 16; off <<= 1) s += __shfl_xor(s, off, 64);
    iz1[r] = 1.0f / s;
  }

  // ---- pass 2 ----
  f32x4 oac[4] = {};
  float z2[4] = {0.f, 0.f, 0.f, 0.f};
  rk0 = *(const us8*)(kg + (size_t)kr0 * 1024 + kc0);
  rk1 = *(const us8*)(kg + (size_t)kr1 * 1024 + kc1);
  us8 rv0 = *(const us8*)(vg + (size_t)kr0 * 1024 + kc0);
  us8 rv1 = *(const us8*)(vg + (size_t)kr1 * 1024 + kc1);
  for (int kt = 0; kt < 16; ++kt) {
    __syncthreads();
    *(us8*)(Ks + kr0 * 72 + kc0) = rk0;
    *(us8*)(Ks + kr1 * 72 + kc1) = rk1;
    *(us8*)(Vt + kr0 * 72 + kc0) = rv0;
    *(us8*)(Vt + kr1 * 72 + kc1) = rv1;
    __syncthreads();
    if (kt < 15) {
      rk0 = *(const us8*)(kg + (size_t)((kt + 1) * 64 + kr0) * 1024 + kc0);
      rk1 = *(const us8*)(kg + (size_t)((kt + 1) * 64 + kr1) * 1024 + kc1);
      rv0 = *(const us8*)(vg + (size_t)kr0 * 1024 + (kt + 1) * 64 + kc0);
      rv1 = *(const us8*)(vg + (size_t)kr1 * 1024 + (kt + 1) * 64 + kc1);
    }
    f32x4 sc[4] = {};
#pragma unroll
    for (int kk = 0; kk < 2; ++kk) {
      const bf16x8 aq = *(const bf16x8*)(Qs + (wave * 16 + l15) * 72 + kk * 32 + quad * 8);
#pragma unroll
      for (int ns = 0; ns < 4; ++ns) {
        const bf16x8 bk_ = *(const bf16x8*)(Ks + (ns * 16 + l15) * 72 + kk * 32 + quad * 8);
        sc[ns] = MFMA16(aq, bk_, sc[ns]);
      }
    }
#pragma unroll
    for (int ns = 0; ns < 4; ++ns)
#pragma unroll
      for (int r = 0; r < 4; ++r) {
        const float p1 = __expf(sc[ns][r]) * iz1[r];   // softmax1 (no max)
        const float e2 = __expf(p1);                   // softmax2 numerator
        z2[r] += e2;
        Ps[wave][(quad * 4 + r) * 68 + ns * 16 + l15] = f2b(e2);
      }
    __asm__ __volatile__("s_waitcnt lgkmcnt(0)" ::: "memory");  // Ps wave-private
#pragma unroll
    for (int kk = 0; kk < 2; ++kk) {
      const ushort_t* pp = &Ps[wave][l15 * 68 + kk * 32 + quad * 8];
      union { us4 hseg[2]; bf16x8 v; } u;
      u.hseg[0] = *(const us4*)pp;
      u.hseg[1] = *(const us4*)(pp + 4);
      const bf16x8 ap = u.v;
#pragma unroll
      for (int ns2 = 0; ns2 < 4; ++ns2) {
        const bf16x8 bv_ = *(const bf16x8*)(Vt + (ns2 * 16 + l15) * 72 + kk * 32 + quad * 8);
        oac[ns2] = MFMA16(ap, bv_, oac[ns2]);
      }
    }
  }

#pragma unroll
  for (int r = 0; r < 4; ++r) {
    float s = z2[r];
#pragma unroll
    for (int off = 1; off < 16; off <<= 1) s += __shfl_xor(s, off, 64);
    z2[r] = s;
  }
#pragma unroll
  for (int ns2 = 0; ns2 < 4; ++ns2) {
    const int d = ns2 * 16 + l15;
#pragma unroll
    for (int r = 0; r < 4; ++r) {
      const int s = q0 + wave * 16 + quad * 4 + r;
      ctx[((size_t)(b * 1024 + s)) * 1024 + h * 64 + d] = f2b(oac[ns2][r] / z2[r]);
    }
  }
}

// ---------------------------------------------------------------------------
// K3: pre = ctx @ Wo_bf^T + bo -> bf16. 64x128 tiles, grid (8,64), prefetched.
// ---------------------------------------------------------------------------
__global__ __launch_bounds__(256, 4) void out_proj_kernel(
    const ushort_t* __restrict__ ctxp, const ushort_t* __restrict__ wo,
    const float* __restrict__ bo, ushort_t* __restrict__ pre) {
  __shared__ __align__(16) ushort_t Asl[64 * 32];
  __shared__ __align__(16) ushort_t Bsl[128 * 32];
  const int tid = threadIdx.x;
  const int wave = tid >> 6, lane = tid & 63;
  const int l15 = lane & 15, quad = lane >> 4;
  const int m0 = blockIdx.y * 64, n0 = blockIdx.x * 128;
  const int wn = wave * 32;

  const int ra = tid >> 2, ca = (tid & 3) * 8;
  const int rb1 = (tid + 256) >> 2;

  us8 va = *(const us8*)(ctxp + (size_t)(m0 + ra) * 1024 + ca);
  us8 vb0 = *(const us8*)(wo + (size_t)(n0 + ra) * 1024 + ca);
  us8 vb1 = *(const us8*)(wo + (size_t)(n0 + rb1) * 1024 + ca);

  f32x4 acc[4][2] = {};
  for (int k0 = 0; k0 < 1024; k0 += 32) {
    __syncthreads();
    *(us8*)(Asl + ra * 32 + ca) = va;
    *(us8*)(Bsl + ra * 32 + ca) = vb0;
    *(us8*)(Bsl + rb1 * 32 + ca) = vb1;
    __syncthreads();
    if (k0 + 32 < 1024) {
      const int k = k0 + 32;
      va  = *(const us8*)(ctxp + (size_t)(m0 + ra) * 1024 + k + ca);
      vb0 = *(const us8*)(wo + (size_t)(n0 + ra) * 1024 + k + ca);
      vb1 = *(const us8*)(wo + (size_t)(n0 + rb1) * 1024 + k + ca);
    }
    bf16x8 af[4], bfr[2];
#pragma unroll
    for (int s = 0; s < 4; ++s)
      af[s] = *(const bf16x8*)(Asl + (s * 16 + l15) * 32 + quad * 8);
#pragma unroll
    for (int s = 0; s < 2; ++s)
      bfr[s] = *(const bf16x8*)(Bsl + (wn + s * 16 + l15) * 32 + quad * 8);
#pragma unroll
    for (int ms = 0; ms < 4; ++ms)
#pragma unroll
      for (int ns = 0; ns < 2; ++ns)
        acc[ms][ns] = MFMA16(af[ms], bfr[ns], acc[ms][ns]);
  }

#pragma unroll
  for (int ns = 0; ns < 2; ++ns) {
    const int col = n0 + wn + ns * 16 + l15;
    const float bv_ = bo[col];
#pragma unroll
    for (int ms = 0; ms < 4; ++ms) {
      const int rowb = m0 + ms * 16 + quad * 4;
#pragma unroll
      for (int r = 0; r < 4; ++r) {
        pre[(size_t)(rowb + r) * 1024 + col] = f2b(acc[ms][ns][r] + bv_);
      }
    }
  }
}

// ---------------------------------------------------------------------------
// K4: out = LayerNorm(pre_bf16 + Q)*g + b -> f32. One block per row.
// ---------------------------------------------------------------------------
__global__ __launch_bounds__(256, 4) void ln_kernel(
    const ushort_t* __restrict__ pre, const float* __restrict__ Q,
    const float* __restrict__ g, const float* __restrict__ bta,
    float* __restrict__ out) {
  const int row = blockIdx.x;
  const int tid = threadIdx.x;
  const size_t base = (size_t)row * 1024 + tid * 4;
  const ushort4 p4 = *(const ushort4*)(pre + base);
  const float4 q4 = *(const float4*)(Q + base);
  float v[4] = {b2f(p4.x) + q4.x, b2f(p4.y) + q4.y,
                b2f(p4.z) + q4.z, b2f(p4.w) + q4.w};
  float s1 = v[0] + v[1] + v[2] + v[3];
  float s2 = v[0]*v[0] + v[1]*v[1] + v[2]*v[2] + v[3]*v[3];
#pragma unroll
  for (int off = 1; off < 64; off <<= 1) {
    s1 += __shfl_xor(s1, off, 64);
    s2 += __shfl_xor(s2, off, 64);
  }
  __shared__ float r1[4], r2[4];
  const int wave = tid >> 6, lane = tid & 63;
  if (lane == 0) { r1[wave] = s1; r2[wave] = s2; }
  __syncthreads();
  const float t1 = r1[0] + r1[1] + r1[2] + r1[3];
  const float t2 = r2[0] + r2[1] + r2[2] + r2[3];
  const float mu = t1 * (1.0f / 1024.0f);
  const float var = t2 * (1.0f / 1024.0f) - mu * mu;
  const float inv = rsqrtf(var + 1e-5f);
  const int c0 = tid * 4;
#pragma unroll
  for (int j = 0; j < 4; ++j) {
    const int c = c0 + j;
    out[(size_t)row * 1024 + c] = (v[j] - mu) * inv * g[c] + bta[c];
  }
}

// ---------------------------------------------------------------------------
extern "C" void kernel_launch(void* const* d_in, const int* in_sizes, int n_in,
                              void* d_out, int out_size, void* d_ws, size_t ws_size,
                              hipStream_t stream) {
  const float* Q  = (const float*)d_in[0];
  const float* K  = (const float*)d_in[1];
  const float* V  = (const float*)d_in[2];
  const float* Wq = (const float*)d_in[3];
  const float* bq = (const float*)d_in[4];
  const float* Wk = (const float*)d_in[5];
  const float* bk = (const float*)d_in[6];
  const float* Wv = (const float*)d_in[7];
  const float* bv = (const float*)d_in[8];
  const float* Wo = (const float*)d_in[9];
  const float* bo = (const float*)d_in[10];
  const float* lg = (const float*)d_in[11];
  const float* lb = (const float*)d_in[12];

  char* ws = (char*)d_ws;                       // 24 MB used
  ushort_t* qb  = (ushort_t*)(ws);                         // [B,S,D] bf16, scaled
  ushort_t* kb  = (ushort_t*)(ws + ((size_t)8  << 20));    // [B,S,D] bf16
  ushort_t* vb  = (ushort_t*)(ws + ((size_t)16 << 20));    // [B,H,dk,S] bf16
  ushort_t* pre = (ushort_t*)(ws);              // bf16, aliases qb (dead by K3)

  ushort_t* dptr  = (ushort_t*)d_out;           // u16 view of 16MB output
  ushort_t* wo_bf = dptr;                       // [0,1M) elems
  ushort_t* wq_bf = dptr + 1048576;             // [1M,2M)
  ushort_t* wk_bf = dptr + 2097152;             // [2M,3M)
  ushort_t* wv_bf = dptr + 3145728;             // [3M,4M)
  ushort_t* ctx   = dptr + 4194304;             // [4M,8M) = bytes [8MB,16MB)
  float*    out   = (float*)d_out;

  cvt4_kernel<<<dim3(512, 4), 256, 0, stream>>>(Wo, Wq, Wk, Wv, dptr);
  qkv_proj_kernel<<<dim3(8, 64, 3), 256, 0, stream>>>(Q, K, V, wq_bf, wk_bf, wv_bf,
                                                      bq, bk, bv, qb, kb, vb);
  attn_kernel<<<dim3(16, 64), 256, 0, stream>>>(qb, kb, vb, ctx);
  out_proj_kernel<<<dim3(8, 64), 256, 0, stream>>>(ctx, wo_bf, bo, pre);
  ln_kernel<<<dim3(4096), 256, 0, stream>>>(pre, Q, lg, lb, out);
}

// Round 14
// 257.668 us; speedup vs baseline: 1.0385x; 1.0385x over previous
//
#include <hip/hip_runtime.h>
#include <cstdint>
#include <cstddef>

// ---------------------------------------------------------------------------
// MultiheadAttention (double-softmax), MI355X. B=4,S=1024,D=1024,H=16.
// Inputs FP32 (dict order), output FP32. r9:317 r12:264.7 r13:267.6 µs.
// r14: XCD-aware block swizzle. r13 counters: qkv freed VALU+occupancy but
// flat => bytes-bound (230 MB moved vs 78 MB ideal; 3x A over-fetch because
// the 8 n-blocks sharing an A-tile round-robin onto 8 different XCDs).
// Swizzle groups sharers onto one XCD: per-XCD working set fits 4 MB L2.
//   K0 cvt4: Wo,Wq,Wk,Wv fp32->bf16 into d_out[0,8MB) (dead until ln)
//   K1 qkv : q,k -> [B,S,D] bf16 (q*0.125); v -> [B,H,dk,S] bf16
//   K2 attn: two-pass double softmax, no-max softmax1 (scores << 88)
//   K3 outp: 64x128 tiles, ctx @ Wo_bf^T + bo -> pre bf16
//   K4 ln  : LayerNorm(pre + Q)*g + b -> d_out f32 [0,16MB)
// ws (24 MB): qb[0,8) kb[8,16) vb[16,24); pre bf16 aliases [0,8) (qb dead).
// d_out u16 view: wo[0,1M) wq[1M,2M) wk[2M,3M) wv[3M,4M) ctx[4M,8M).
// ---------------------------------------------------------------------------

typedef unsigned short ushort_t;
typedef __attribute__((ext_vector_type(8))) short bf16x8;     // MFMA A/B frag
typedef __attribute__((ext_vector_type(8))) unsigned short us8;
typedef __attribute__((ext_vector_type(4))) unsigned short us4;
typedef __attribute__((ext_vector_type(4))) float f32x4;      // MFMA C/D frag

#define MFMA16(a, b, c) __builtin_amdgcn_mfma_f32_16x16x32_bf16((a), (b), (c), 0, 0, 0)

__device__ __forceinline__ float b2f(ushort_t u) {
  union { unsigned int i; float f; } x; x.i = ((unsigned int)u) << 16; return x.f;
}
__device__ __forceinline__ ushort_t f2b(float f) {
  union { unsigned int i; float f; } x; x.f = f;
  unsigned int r = (x.i + 0x7FFFu + ((x.i >> 16) & 1u)) >> 16;  // RNE
  return (ushort_t)r;
}
__device__ __forceinline__ us8 cvt8(float4 a, float4 b) {
  us8 r;
  r[0] = f2b(a.x); r[1] = f2b(a.y); r[2] = f2b(a.z); r[3] = f2b(a.w);
  r[4] = f2b(b.x); r[5] = f2b(b.y); r[6] = f2b(b.z); r[7] = f2b(b.w);
  return r;
}

// ---------------------------------------------------------------------------
// K0: convert 4 weight matrices (1M fp32 elems each) to bf16.
// ---------------------------------------------------------------------------
__global__ __launch_bounds__(256, 8) void cvt4_kernel(
    const float* __restrict__ w0, const float* __restrict__ w1,
    const float* __restrict__ w2, const float* __restrict__ w3,
    ushort_t* __restrict__ dst) {
  const int which = blockIdx.y;
  const float* src = (which == 0) ? w0 : (which == 1) ? w1 : (which == 2) ? w2 : w3;
  const int i = (blockIdx.x * 256 + threadIdx.x) * 8;
  const float4 a = *(const float4*)(src + i);
  const float4 b = *(const float4*)(src + i + 4);
  *(us8*)(dst + (size_t)which * 1048576 + i) = cvt8(a, b);
}

// ---------------------------------------------------------------------------
// K1: Q/K/V projections. 64x128 tiles, grid (512,1,3).
// XCD swizzle: xcd = bid&7 owns m-tiles [xcd*8, xcd*8+8) x all 8 n-tiles
// (per-XCD: 2MB A + 2MB B = 4MB L2). A fp32 (cvt in staging, prefetched);
// B bf16 (pure copy). q,k -> [B,S,D]; v -> [B,H,dk,S].
// ---------------------------------------------------------------------------
__global__ __launch_bounds__(256, 6) void qkv_proj_kernel(
    const float* __restrict__ Qin, const float* __restrict__ Kin,
    const float* __restrict__ Vin,
    const ushort_t* __restrict__ wq, const ushort_t* __restrict__ wk,
    const ushort_t* __restrict__ wv,
    const float* __restrict__ bq, const float* __restrict__ bk,
    const float* __restrict__ bv,
    ushort_t* __restrict__ qb, ushort_t* __restrict__ kb,
    ushort_t* __restrict__ vb) {
  __shared__ __align__(16) ushort_t Asl[64 * 32];
  __shared__ __align__(16) ushort_t Bsl[128 * 32];
  const float* A; const ushort_t* W; const float* bias; float scale;
  if (blockIdx.z == 0)      { A = Qin; W = wq; bias = bq; scale = 0.125f; }
  else if (blockIdx.z == 1) { A = Kin; W = wk; bias = bk; scale = 1.0f; }
  else                      { A = Vin; W = wv; bias = bv; scale = 1.0f; }
  // XCD-aware swizzle (assumes XCD = linear blockIdx % 8; z stride 512 ≡ 0 mod 8)
  const int l = blockIdx.x;
  const int xcd = l & 7, ii = l >> 3;
  const int m0 = (xcd * 8 + (ii >> 3)) * 64;
  const int n0 = (ii & 7) * 128;
  const int tid = threadIdx.x;
  const int wave = tid >> 6, lane = tid & 63;
  const int l15 = lane & 15, quad = lane >> 4;
  const int wn = wave * 32;

  const int ra = tid >> 2, ca = (tid & 3) * 8;
  const int rb1 = (tid + 256) >> 2;                    // B rows 64..127

  const float* Ap = A + (size_t)(m0 + ra) * 1024 + ca;
  const ushort_t* Bp0 = W + (size_t)(n0 + ra) * 1024 + ca;
  const ushort_t* Bp1 = W + (size_t)(n0 + rb1) * 1024 + ca;

  float4 al = *(const float4*)(Ap), ah = *(const float4*)(Ap + 4);
  us8 rb0v = *(const us8*)(Bp0);
  us8 rb1v = *(const us8*)(Bp1);

  f32x4 acc[4][2] = {};
  for (int k0 = 0; k0 < 1024; k0 += 32) {
    __syncthreads();
    *(us8*)(Asl + ra * 32 + ca) = cvt8(al, ah);
    *(us8*)(Bsl + ra * 32 + ca) = rb0v;
    *(us8*)(Bsl + rb1 * 32 + ca) = rb1v;
    __syncthreads();
    if (k0 + 32 < 1024) {  // prefetch next K-tile (overlaps MFMA)
      const int k = k0 + 32;
      al = *(const float4*)(Ap + k); ah = *(const float4*)(Ap + k + 4);
      rb0v = *(const us8*)(Bp0 + k);
      rb1v = *(const us8*)(Bp1 + k);
    }
    bf16x8 af[4], bfr[2];
#pragma unroll
    for (int s = 0; s < 4; ++s)
      af[s] = *(const bf16x8*)(Asl + (s * 16 + l15) * 32 + quad * 8);
#pragma unroll
    for (int s = 0; s < 2; ++s)
      bfr[s] = *(const bf16x8*)(Bsl + (wn + s * 16 + l15) * 32 + quad * 8);
#pragma unroll
    for (int ms = 0; ms < 4; ++ms)
#pragma unroll
      for (int ns = 0; ns < 2; ++ns)
        acc[ms][ns] = MFMA16(af[ms], bfr[ns], acc[ms][ns]);
  }

  if (blockIdx.z != 2) {
    ushort_t* outp = (blockIdx.z == 0) ? qb : kb;
#pragma unroll
    for (int ns = 0; ns < 2; ++ns) {
      const int col = n0 + wn + ns * 16 + l15;
      const float bv_ = bias[col];
#pragma unroll
      for (int ms = 0; ms < 4; ++ms) {
        const int rowb = m0 + ms * 16 + quad * 4;
#pragma unroll
        for (int r = 0; r < 4; ++r) {
          outp[(size_t)(rowb + r) * 1024 + col] =
              f2b((acc[ms][ns][r] + bv_) * scale);
        }
      }
    }
  } else {
    // V transposed: vb[((b*16+h)*64 + d)*1024 + s]
#pragma unroll
    for (int ns = 0; ns < 2; ++ns) {
      const int col = n0 + wn + ns * 16 + l15;
      const float bv_ = bias[col];
      const int h = col >> 6, d = col & 63;
#pragma unroll
      for (int ms = 0; ms < 4; ++ms) {
        const int i0 = m0 + ms * 16 + quad * 4;
        const int b = i0 >> 10, s0 = i0 & 1023;
        us4 pack;
#pragma unroll
        for (int r = 0; r < 4; ++r) pack[r] = f2b(acc[ms][ns][r] + bv_);
        *(us4*)(vb + ((size_t)(b * 16 + h) * 64 + d) * 1024 + s0) = pack;
      }
    }
  }
}

// ---------------------------------------------------------------------------
// K2: attention, double softmax. 64-row Q tile, grid 1024 (flat, swizzled:
// xcd owns 8 bh values x all 16 q-tiles -> per-XCD K/V = 2MB in L2).
// Pass 1: Z1 = sum(exp(s)) only (no max). Pass 2: e2 = exp(exp(s)/Z1), PV.
// ---------------------------------------------------------------------------
__global__ __launch_bounds__(256, 4) void attn_kernel(
    const ushort_t* __restrict__ qb, const ushort_t* __restrict__ kb,
    const ushort_t* __restrict__ vb, ushort_t* __restrict__ ctx) {
  __shared__ __align__(16) ushort_t Qs[64 * 72];
  __shared__ __align__(16) ushort_t Ks[64 * 72];
  __shared__ __align__(16) ushort_t Vt[64 * 72];
  __shared__ __align__(16) ushort_t Ps[4][16 * 68];

  const int tid = threadIdx.x, wave = tid >> 6, lane = tid & 63;
  const int l15 = lane & 15, quad = lane >> 4;
  // XCD-aware swizzle
  const int l = blockIdx.x;
  const int xcd = l & 7, ii = l >> 3;
  const int bh = xcd * 8 + (ii >> 4);
  const int q0 = (ii & 15) * 64;
  const int b = bh >> 4, h = bh & 15;
  const ushort_t* qg = qb + ((size_t)b << 20) + h * 64;
  const ushort_t* kg = kb + ((size_t)b << 20) + h * 64;
  const ushort_t* vg = vb + ((size_t)bh << 16);   // [dk][S]

  const int kr0 = tid >> 3, kc0 = (tid & 7) * 8;
  const int kr1 = (tid + 256) >> 3, kc1 = kc0;

  *(us8*)(Qs + kr0 * 72 + kc0) = *(const us8*)(qg + (size_t)(q0 + kr0) * 1024 + kc0);
  *(us8*)(Qs + kr1 * 72 + kc1) = *(const us8*)(qg + (size_t)(q0 + kr1) * 1024 + kc1);

  // ---- pass 1: Z1 only ----
  float z1[4] = {0.f, 0.f, 0.f, 0.f};
  us8 rk0 = *(const us8*)(kg + (size_t)kr0 * 1024 + kc0);
  us8 rk1 = *(const us8*)(kg + (size_t)kr1 * 1024 + kc1);
  for (int kt = 0; kt < 16; ++kt) {
    __syncthreads();
    *(us8*)(Ks + kr0 * 72 + kc0) = rk0;
    *(us8*)(Ks + kr1 * 72 + kc1) = rk1;
    __syncthreads();
    if (kt < 15) {
      rk0 = *(const us8*)(kg + (size_t)((kt + 1) * 64 + kr0) * 1024 + kc0);
      rk1 = *(const us8*)(kg + (size_t)((kt + 1) * 64 + kr1) * 1024 + kc1);
    }
    f32x4 sc[4] = {};
#pragma unroll
    for (int kk = 0; kk < 2; ++kk) {
      const bf16x8 aq = *(const bf16x8*)(Qs + (wave * 16 + l15) * 72 + kk * 32 + quad * 8);
#pragma unroll
      for (int ns = 0; ns < 4; ++ns) {
        const bf16x8 bk_ = *(const bf16x8*)(Ks + (ns * 16 + l15) * 72 + kk * 32 + quad * 8);
        sc[ns] = MFMA16(aq, bk_, sc[ns]);
      }
    }
#pragma unroll
    for (int ns = 0; ns < 4; ++ns)
#pragma unroll
      for (int r = 0; r < 4; ++r) z1[r] += __expf(sc[ns][r]);
  }
  float iz1[4];
#pragma unroll
  for (int r = 0; r < 4; ++r) {
    float s = z1[r];
#pragma unroll
    for (int off = 1; off < 16; off <<= 1) s += __shfl_xor(s, off, 64);
    iz1[r] = 1.0f / s;
  }

  // ---- pass 2 ----
  f32x4 oac[4] = {};
  float z2[4] = {0.f, 0.f, 0.f, 0.f};
  rk0 = *(const us8*)(kg + (size_t)kr0 * 1024 + kc0);
  rk1 = *(const us8*)(kg + (size_t)kr1 * 1024 + kc1);
  us8 rv0 = *(const us8*)(vg + (size_t)kr0 * 1024 + kc0);
  us8 rv1 = *(const us8*)(vg + (size_t)kr1 * 1024 + kc1);
  for (int kt = 0; kt < 16; ++kt) {
    __syncthreads();
    *(us8*)(Ks + kr0 * 72 + kc0) = rk0;
    *(us8*)(Ks + kr1 * 72 + kc1) = rk1;
    *(us8*)(Vt + kr0 * 72 + kc0) = rv0;
    *(us8*)(Vt + kr1 * 72 + kc1) = rv1;
    __syncthreads();
    if (kt < 15) {
      rk0 = *(const us8*)(kg + (size_t)((kt + 1) * 64 + kr0) * 1024 + kc0);
      rk1 = *(const us8*)(kg + (size_t)((kt + 1) * 64 + kr1) * 1024 + kc1);
      rv0 = *(const us8*)(vg + (size_t)kr0 * 1024 + (kt + 1) * 64 + kc0);
      rv1 = *(const us8*)(vg + (size_t)kr1 * 1024 + (kt + 1) * 64 + kc1);
    }
    f32x4 sc[4] = {};
#pragma unroll
    for (int kk = 0; kk < 2; ++kk) {
      const bf16x8 aq = *(const bf16x8*)(Qs + (wave * 16 + l15) * 72 + kk * 32 + quad * 8);
#pragma unroll
      for (int ns = 0; ns < 4; ++ns) {
        const bf16x8 bk_ = *(const bf16x8*)(Ks + (ns * 16 + l15) * 72 + kk * 32 + quad * 8);
        sc[ns] = MFMA16(aq, bk_, sc[ns]);
      }
    }
#pragma unroll
    for (int ns = 0; ns < 4; ++ns)
#pragma unroll
      for (int r = 0; r < 4; ++r) {
        const float p1 = __expf(sc[ns][r]) * iz1[r];   // softmax1 (no max)
        const float e2 = __expf(p1);                   // softmax2 numerator
        z2[r] += e2;
        Ps[wave][(quad * 4 + r) * 68 + ns * 16 + l15] = f2b(e2);
      }
    __asm__ __volatile__("s_waitcnt lgkmcnt(0)" ::: "memory");  // Ps wave-private
#pragma unroll
    for (int kk = 0; kk < 2; ++kk) {
      const ushort_t* pp = &Ps[wave][l15 * 68 + kk * 32 + quad * 8];
      union { us4 hseg[2]; bf16x8 v; } u;
      u.hseg[0] = *(const us4*)pp;
      u.hseg[1] = *(const us4*)(pp + 4);
      const bf16x8 ap = u.v;
#pragma unroll
      for (int ns2 = 0; ns2 < 4; ++ns2) {
        const bf16x8 bv_ = *(const bf16x8*)(Vt + (ns2 * 16 + l15) * 72 + kk * 32 + quad * 8);
        oac[ns2] = MFMA16(ap, bv_, oac[ns2]);
      }
    }
  }

#pragma unroll
  for (int r = 0; r < 4; ++r) {
    float s = z2[r];
#pragma unroll
    for (int off = 1; off < 16; off <<= 1) s += __shfl_xor(s, off, 64);
    z2[r] = s;
  }
#pragma unroll
  for (int ns2 = 0; ns2 < 4; ++ns2) {
    const int d = ns2 * 16 + l15;
#pragma unroll
    for (int r = 0; r < 4; ++r) {
      const int s = q0 + wave * 16 + quad * 4 + r;
      ctx[((size_t)(b * 1024 + s)) * 1024 + h * 64 + d] = f2b(oac[ns2][r] / z2[r]);
    }
  }
}

// ---------------------------------------------------------------------------
// K3: pre = ctx @ Wo_bf^T + bo -> bf16. 64x128 tiles, grid 512 (swizzled
// like qkv: per-XCD 2MB ctx + 2MB Wo in L2), prefetched.
// ---------------------------------------------------------------------------
__global__ __launch_bounds__(256, 4) void out_proj_kernel(
    const ushort_t* __restrict__ ctxp, const ushort_t* __restrict__ wo,
    const float* __restrict__ bo, ushort_t* __restrict__ pre) {
  __shared__ __align__(16) ushort_t Asl[64 * 32];
  __shared__ __align__(16) ushort_t Bsl[128 * 32];
  const int tid = threadIdx.x;
  const int wave = tid >> 6, lane = tid & 63;
  const int l15 = lane & 15, quad = lane >> 4;
  // XCD-aware swizzle
  const int l = blockIdx.x;
  const int xcd = l & 7, ii = l >> 3;
  const int m0 = (xcd * 8 + (ii >> 3)) * 64;
  const int n0 = (ii & 7) * 128;
  const int wn = wave * 32;

  const int ra = tid >> 2, ca = (tid & 3) * 8;
  const int rb1 = (tid + 256) >> 2;

  us8 va = *(const us8*)(ctxp + (size_t)(m0 + ra) * 1024 + ca);
  us8 vb0 = *(const us8*)(wo + (size_t)(n0 + ra) * 1024 + ca);
  us8 vb1 = *(const us8*)(wo + (size_t)(n0 + rb1) * 1024 + ca);

  f32x4 acc[4][2] = {};
  for (int k0 = 0; k0 < 1024; k0 += 32) {
    __syncthreads();
    *(us8*)(Asl + ra * 32 + ca) = va;
    *(us8*)(Bsl + ra * 32 + ca) = vb0;
    *(us8*)(Bsl + rb1 * 32 + ca) = vb1;
    __syncthreads();
    if (k0 + 32 < 1024) {
      const int k = k0 + 32;
      va  = *(const us8*)(ctxp + (size_t)(m0 + ra) * 1024 + k + ca);
      vb0 = *(const us8*)(wo + (size_t)(n0 + ra) * 1024 + k + ca);
      vb1 = *(const us8*)(wo + (size_t)(n0 + rb1) * 1024 + k + ca);
    }
    bf16x8 af[4], bfr[2];
#pragma unroll
    for (int s = 0; s < 4; ++s)
      af[s] = *(const bf16x8*)(Asl + (s * 16 + l15) * 32 + quad * 8);
#pragma unroll
    for (int s = 0; s < 2; ++s)
      bfr[s] = *(const bf16x8*)(Bsl + (wn + s * 16 + l15) * 32 + quad * 8);
#pragma unroll
    for (int ms = 0; ms < 4; ++ms)
#pragma unroll
      for (int ns = 0; ns < 2; ++ns)
        acc[ms][ns] = MFMA16(af[ms], bfr[ns], acc[ms][ns]);
  }

#pragma unroll
  for (int ns = 0; ns < 2; ++ns) {
    const int col = n0 + wn + ns * 16 + l15;
    const float bv_ = bo[col];
#pragma unroll
    for (int ms = 0; ms < 4; ++ms) {
      const int rowb = m0 + ms * 16 + quad * 4;
#pragma unroll
      for (int r = 0; r < 4; ++r) {
        pre[(size_t)(rowb + r) * 1024 + col] = f2b(acc[ms][ns][r] + bv_);
      }
    }
  }
}

// ---------------------------------------------------------------------------
// K4: out = LayerNorm(pre_bf16 + Q)*g + b -> f32. One block per row.
// ---------------------------------------------------------------------------
__global__ __launch_bounds__(256, 4) void ln_kernel(
    const ushort_t* __restrict__ pre, const float* __restrict__ Q,
    const float* __restrict__ g, const float* __restrict__ bta,
    float* __restrict__ out) {
  const int row = blockIdx.x;
  const int tid = threadIdx.x;
  const size_t base = (size_t)row * 1024 + tid * 4;
  const ushort4 p4 = *(const ushort4*)(pre + base);
  const float4 q4 = *(const float4*)(Q + base);
  float v[4] = {b2f(p4.x) + q4.x, b2f(p4.y) + q4.y,
                b2f(p4.z) + q4.z, b2f(p4.w) + q4.w};
  float s1 = v[0] + v[1] + v[2] + v[3];
  float s2 = v[0]*v[0] + v[1]*v[1] + v[2]*v[2] + v[3]*v[3];
#pragma unroll
  for (int off = 1; off < 64; off <<= 1) {
    s1 += __shfl_xor(s1, off, 64);
    s2 += __shfl_xor(s2, off, 64);
  }
  __shared__ float r1[4], r2[4];
  const int wave = tid >> 6, lane = tid & 63;
  if (lane == 0) { r1[wave] = s1; r2[wave] = s2; }
  __syncthreads();
  const float t1 = r1[0] + r1[1] + r1[2] + r1[3];
  const float t2 = r2[0] + r2[1] + r2[2] + r2[3];
  const float mu = t1 * (1.0f / 1024.0f);
  const float var = t2 * (1.0f / 1024.0f) - mu * mu;
  const float inv = rsqrtf(var + 1e-5f);
  const int c0 = tid * 4;
#pragma unroll
  for (int j = 0; j < 4; ++j) {
    const int c = c0 + j;
    out[(size_t)row * 1024 + c] = (v[j] - mu) * inv * g[c] + bta[c];
  }
}

// ---------------------------------------------------------------------------
extern "C" void kernel_launch(void* const* d_in, const int* in_sizes, int n_in,
                              void* d_out, int out_size, void* d_ws, size_t ws_size,
                              hipStream_t stream) {
  const float* Q  = (const float*)d_in[0];
  const float* K  = (const float*)d_in[1];
  const float* V  = (const float*)d_in[2];
  const float* Wq = (const float*)d_in[3];
  const float* bq = (const float*)d_in[4];
  const float* Wk = (const float*)d_in[5];
  const float* bk = (const float*)d_in[6];
  const float* Wv = (const float*)d_in[7];
  const float* bv = (const float*)d_in[8];
  const float* Wo = (const float*)d_in[9];
  const float* bo = (const float*)d_in[10];
  const float* lg = (const float*)d_in[11];
  const float* lb = (const float*)d_in[12];

  char* ws = (char*)d_ws;                       // 24 MB used
  ushort_t* qb  = (ushort_t*)(ws);                         // [B,S,D] bf16, scaled
  ushort_t* kb  = (ushort_t*)(ws + ((size_t)8  << 20));    // [B,S,D] bf16
  ushort_t* vb  = (ushort_t*)(ws + ((size_t)16 << 20));    // [B,H,dk,S] bf16
  ushort_t* pre = (ushort_t*)(ws);              // bf16, aliases qb (dead by K3)

  ushort_t* dptr  = (ushort_t*)d_out;           // u16 view of 16MB output
  ushort_t* wo_bf = dptr;                       // [0,1M) elems
  ushort_t* wq_bf = dptr + 1048576;             // [1M,2M)
  ushort_t* wk_bf = dptr + 2097152;             // [2M,3M)
  ushort_t* wv_bf = dptr + 3145728;             // [3M,4M)
  ushort_t* ctx   = dptr + 4194304;             // [4M,8M) = bytes [8MB,16MB)
  float*    out   = (float*)d_out;

  cvt4_kernel<<<dim3(512, 4), 256, 0, stream>>>(Wo, Wq, Wk, Wv, dptr);
  qkv_proj_kernel<<<dim3(512, 1, 3), 256, 0, stream>>>(Q, K, V, wq_bf, wk_bf, wv_bf,
                                                       bq, bk, bv, qb, kb, vb);
  attn_kernel<<<dim3(1024), 256, 0, stream>>>(qb, kb, vb, ctx);
  out_proj_kernel<<<dim3(512), 256, 0, stream>>>(ctx, wo_bf, bo, pre);
  ln_kernel<<<dim3(4096), 256, 0, stream>>>(pre, Q, lg, lb, out);
}